// Round 1
// baseline (1130.243 us; speedup 1.0000x reference)
//
#include <hip/hip_runtime.h>
#include <hip/hip_bf16.h>
#include <cstdint>

// Problem constants (from reference): x (8,2048,4096) fp32, W (4096,4096),
// A (4096,16), B (16,4096), bias (4096). out (8,2048,4096) fp32.
#define M_DIM 16384
#define K_DIM 4096
#define N_DIM 4096
#define RANK  16

// GEMM tile config (m97 ladder structure: 128x128 tile, BK=32, 4 waves)
#define BM 128
#define BN 128
#define BK 32

typedef __bf16 bf16x8 __attribute__((ext_vector_type(8)));
typedef float  f32x4  __attribute__((ext_vector_type(4)));

// round-to-nearest-even f32 -> bf16 bits (inputs are finite normals; no NaN path)
__device__ __forceinline__ uint16_t f2bf(float f) {
    union { float f; uint32_t u; } v; v.f = f;
    uint32_t u = v.u;
    return (uint16_t)((u + 0x7FFFu + ((u >> 16) & 1u)) >> 16);
}

// ---------------------------------------------------------------------------
// Pass 1: x (fp32) -> bf16. 8 elements/thread: 32B read, 16B write per lane.
// ---------------------------------------------------------------------------
__global__ void cvt_x_kernel(const float* __restrict__ x, uint16_t* __restrict__ xb) {
    size_t g = (size_t)blockIdx.x * blockDim.x + threadIdx.x;
    const float4* xv = (const float4*)x;
    float4 a = xv[2 * g];
    float4 b = xv[2 * g + 1];
    union { uint4 u; uint16_t h[8]; } p;
    p.h[0] = f2bf(a.x); p.h[1] = f2bf(a.y); p.h[2] = f2bf(a.z); p.h[3] = f2bf(a.w);
    p.h[4] = f2bf(b.x); p.h[5] = f2bf(b.y); p.h[6] = f2bf(b.z); p.h[7] = f2bf(b.w);
    ((uint4*)xb)[g] = p.u;
}

// ---------------------------------------------------------------------------
// Pass 2: Weff[n][k] = W[n][k] + sum_r A[k][r]*B[r][n], cast to bf16.
// One block per n; B column (16 floats) staged in LDS; A row read as 4x float4.
// ---------------------------------------------------------------------------
__global__ void prep_w_kernel(const float* __restrict__ W, const float* __restrict__ A,
                              const float* __restrict__ B, uint16_t* __restrict__ wb) {
    const int n = blockIdx.x;
    __shared__ float bcol[RANK];
    if (threadIdx.x < RANK) bcol[threadIdx.x] = B[threadIdx.x * N_DIM + n];
    __syncthreads();
    float bc[RANK];
#pragma unroll
    for (int r = 0; r < RANK; r++) bc[r] = bcol[r];

    for (int k = threadIdx.x; k < K_DIM; k += blockDim.x) {
        const float4* ar = (const float4*)(A + (size_t)k * RANK);
        float acc = W[(size_t)n * K_DIM + k];
#pragma unroll
        for (int q = 0; q < 4; q++) {
            float4 a4 = ar[q];
            acc += a4.x * bc[4*q+0] + a4.y * bc[4*q+1] + a4.z * bc[4*q+2] + a4.w * bc[4*q+3];
        }
        wb[(size_t)n * K_DIM + k] = f2bf(acc);
    }
}

// ---------------------------------------------------------------------------
// Main GEMM: C[m][n] = sum_k Xb[m][k]*Wb[n][k] + bias[n]   (bf16 in, fp32 out)
// m97 structure: 128x128 block tile, BK=32, 256 threads = 2x2 waves,
// each wave 64x64 = 4x4 of 16x16x32 MFMA. global_load_lds width-16 staging.
// ---------------------------------------------------------------------------
__device__ __forceinline__ void gload_lds16(const void* g, void* l) {
    __builtin_amdgcn_global_load_lds(
        (const __attribute__((address_space(1))) void*)g,
        (__attribute__((address_space(3))) void*)l,
        16, 0, 0);
}

__global__ __launch_bounds__(256, 2)
void gemm_bt_bias(const uint16_t* __restrict__ Xb,   // M x K, row-major
                  const uint16_t* __restrict__ Wb,   // N x K, row-major
                  const float* __restrict__ bias,    // N
                  float* __restrict__ C) {           // M x N
    __shared__ uint16_t As[BM * BK];   // 8 KB
    __shared__ uint16_t Bs[BN * BK];   // 8 KB

    const int tid  = threadIdx.x;
    const int wave = tid >> 6;
    const int lane = tid & 63;

    const int bm = blockIdx.y * BM;
    const int bn = blockIdx.x * BN;

    const int wm = (wave >> 1) * 64;   // wave's row offset in tile
    const int wn = (wave & 1) * 64;    // wave's col offset in tile

    // Staging: 128 rows x 64B per tile = 512 x 16B chunks; thread covers 2.
    // LDS dest must be contiguous in lane order (wave-uniform base + lane*16).
    const int c0 = tid;         // chunks 0..255
    const int c1 = tid + 256;   // chunks 256..511
    const int r0 = c0 >> 2, q0 = c0 & 3;
    const int r1 = c1 >> 2, q1 = c1 & 3;

    const uint16_t* xg0 = Xb + (size_t)(bm + r0) * K_DIM + q0 * 8;
    const uint16_t* xg1 = Xb + (size_t)(bm + r1) * K_DIM + q1 * 8;
    const uint16_t* wg0 = Wb + (size_t)(bn + r0) * K_DIM + q0 * 8;
    const uint16_t* wg1 = Wb + (size_t)(bn + r1) * K_DIM + q1 * 8;

    uint16_t* lA0 = As + c0 * 8;
    uint16_t* lA1 = As + c1 * 8;
    uint16_t* lB0 = Bs + c0 * 8;
    uint16_t* lB1 = Bs + c1 * 8;

    const int m15 = lane & 15;     // fragment row/col index
    const int kq  = lane >> 4;     // k-quad 0..3
    const int koff = kq * 8;       // element offset of fragment in LDS row

    f32x4 acc[4][4];
    const f32x4 zero = {0.f, 0.f, 0.f, 0.f};
#pragma unroll
    for (int i = 0; i < 4; i++)
#pragma unroll
        for (int j = 0; j < 4; j++) acc[i][j] = zero;

    for (int k0 = 0; k0 < K_DIM; k0 += BK) {
        gload_lds16(xg0 + k0, lA0);
        gload_lds16(xg1 + k0, lA1);
        gload_lds16(wg0 + k0, lB0);
        gload_lds16(wg1 + k0, lB1);
        __syncthreads();   // compiler emits vmcnt(0) drain before barrier

        bf16x8 af[4], bfr[4];
#pragma unroll
        for (int i = 0; i < 4; i++)
            af[i] = *(const bf16x8*)&As[(wm + i * 16 + m15) * BK + koff];
#pragma unroll
        for (int j = 0; j < 4; j++)
            bfr[j] = *(const bf16x8*)&Bs[(wn + j * 16 + m15) * BK + koff];

#pragma unroll
        for (int i = 0; i < 4; i++)
#pragma unroll
            for (int j = 0; j < 4; j++)
                acc[i][j] = __builtin_amdgcn_mfma_f32_16x16x32_bf16(af[i], bfr[j], acc[i][j], 0, 0, 0);

        __syncthreads();   // protect LDS before next stage overwrites
    }

    // Epilogue: C/D layout col = lane&15, row = (lane>>4)*4 + reg  [m89/m91]
#pragma unroll
    for (int j = 0; j < 4; j++) {
        const int col = bn + wn + j * 16 + m15;
        const float bv = bias[col];
#pragma unroll
        for (int i = 0; i < 4; i++) {
            const int row0 = bm + wm + i * 16 + kq * 4;
#pragma unroll
            for (int r = 0; r < 4; r++) {
                C[(size_t)(row0 + r) * N_DIM + col] = acc[i][j][r] + bv;
            }
        }
    }
}

extern "C" void kernel_launch(void* const* d_in, const int* in_sizes, int n_in,
                              void* d_out, int out_size, void* d_ws, size_t ws_size,
                              hipStream_t stream) {
    const float* x    = (const float*)d_in[0];
    const float* A    = (const float*)d_in[1];
    const float* B    = (const float*)d_in[2];
    const float* W    = (const float*)d_in[3];
    const float* bias = (const float*)d_in[4];
    float* out = (float*)d_out;

    // Workspace: Xb (M*K bf16 = 128 MiB) then Wb (N*K bf16 = 32 MiB)
    uint16_t* Xb = (uint16_t*)d_ws;
    uint16_t* Wb = (uint16_t*)((char*)d_ws + (size_t)M_DIM * K_DIM * sizeof(uint16_t));

    cvt_x_kernel<<<(M_DIM * K_DIM) / (8 * 256), 256, 0, stream>>>(x, Xb);
    prep_w_kernel<<<N_DIM, 256, 0, stream>>>(W, A, B, Wb);

    dim3 grid(N_DIM / BN, M_DIM / BM);
    gemm_bt_bias<<<grid, 256, 0, stream>>>(Xb, Wb, bias, out);
}

// Round 2
// 1030.071 us; speedup vs baseline: 1.0972x; 1.0972x over previous
//
#include <hip/hip_runtime.h>
#include <hip/hip_bf16.h>
#include <cstdint>

// LoRA forward: out = x@W^T + (x@A)@B + bias, folded to one bf16 GEMM
// x (16384,4096) fp32, W (4096,4096), A (4096,16), B (16,4096), bias (4096).
#define M_DIM 16384
#define K_DIM 4096
#define N_DIM 4096
#define RANK  16

// GEMM tile: 128x128, BK=64 (half the barriers of m97's BK=32), 4 waves.
#define BM 128
#define BN 128
#define BK 64

typedef __bf16 bf16x8 __attribute__((ext_vector_type(8)));
typedef float  f32x4  __attribute__((ext_vector_type(4)));

__device__ __forceinline__ uint16_t f2bf(float f) {
    union { float f; uint32_t u; } v; v.f = f;
    uint32_t u = v.u;
    return (uint16_t)((u + 0x7FFFu + ((u >> 16) & 1u)) >> 16);
}

// ---------------------------------------------------------------------------
// Fused prep: blocks [0, 32768) convert x -> bf16 (8 elem/thread);
// blocks [32768, 36864) build Weff[n][k] = W[n][k] + sum_r A[k][r]*B[r][n] -> bf16.
// Fusing overlaps the two memory-bound passes in one dispatch.
// ---------------------------------------------------------------------------
#define CVT_BLOCKS (M_DIM * K_DIM / (8 * 256))   // 32768

__global__ void prep_kernel(const float* __restrict__ x, uint16_t* __restrict__ xb,
                            const float* __restrict__ W, const float* __restrict__ A,
                            const float* __restrict__ B, uint16_t* __restrict__ wb) {
    if (blockIdx.x < CVT_BLOCKS) {
        size_t g = (size_t)blockIdx.x * blockDim.x + threadIdx.x;
        const float4* xv = (const float4*)x;
        float4 a = xv[2 * g];
        float4 b = xv[2 * g + 1];
        union { uint4 u; uint16_t h[8]; } p;
        p.h[0] = f2bf(a.x); p.h[1] = f2bf(a.y); p.h[2] = f2bf(a.z); p.h[3] = f2bf(a.w);
        p.h[4] = f2bf(b.x); p.h[5] = f2bf(b.y); p.h[6] = f2bf(b.z); p.h[7] = f2bf(b.w);
        ((uint4*)xb)[g] = p.u;
    } else {
        const int n = blockIdx.x - CVT_BLOCKS;
        __shared__ float bcol[RANK];
        if (threadIdx.x < RANK) bcol[threadIdx.x] = B[threadIdx.x * N_DIM + n];
        __syncthreads();
        float bc[RANK];
#pragma unroll
        for (int r = 0; r < RANK; r++) bc[r] = bcol[r];
        for (int k = threadIdx.x; k < K_DIM; k += blockDim.x) {
            const float4* ar = (const float4*)(A + (size_t)k * RANK);
            float acc = W[(size_t)n * K_DIM + k];
#pragma unroll
            for (int q = 0; q < 4; q++) {
                float4 a4 = ar[q];
                acc += a4.x * bc[4*q+0] + a4.y * bc[4*q+1] + a4.z * bc[4*q+2] + a4.w * bc[4*q+3];
            }
            wb[(size_t)n * K_DIM + k] = f2bf(acc);
        }
    }
}

// ---------------------------------------------------------------------------
// GEMM: C[m][n] = sum_k Xb[m][k]*Wb[n][k] + bias[n]  (bf16 in, fp32 out)
// 128x128 tile, BK=64, 2x2 waves each computing 64x64 via 4x4x2 of
// mfma_f32_16x16x32_bf16. global_load_lds width-16 staging with XOR chunk
// swizzle (q_lds = q_g ^ (row&7)) so fragment ds_read_b128s are conflict-free.
// ---------------------------------------------------------------------------
__device__ __forceinline__ void gload_lds16(const void* g, void* l) {
    __builtin_amdgcn_global_load_lds(
        (const __attribute__((address_space(1))) void*)g,
        (__attribute__((address_space(3))) void*)l,
        16, 0, 0);
}

__global__ __launch_bounds__(256, 3)
void gemm_bt_bias(const uint16_t* __restrict__ Xb,   // M x K, row-major
                  const uint16_t* __restrict__ Wb,   // N x K, row-major
                  const float* __restrict__ bias,    // N
                  float* __restrict__ C) {           // M x N
    __shared__ uint16_t As[BM * BK];   // 16 KB
    __shared__ uint16_t Bs[BN * BK];   // 16 KB

    const int tid  = threadIdx.x;
    const int wave = tid >> 6;
    const int lane = tid & 63;

    const int bm = blockIdx.y * BM;
    const int bn = blockIdx.x * BN;

    const int wm = (wave >> 1) * 64;
    const int wn = (wave & 1) * 64;

    // Staging: per matrix per K-iter, 128 rows x 128 B = 1024 chunks of 16 B.
    // Thread covers chunks c = tid + 256*s, s=0..3. LDS dest = base + c*16
    // (lane-contiguous as global_load_lds requires). Global source chunk is
    // XOR-swizzled: q_g = q_lds ^ (row & 7).
    const uint16_t* xg[4];
    const uint16_t* wg[4];
    uint16_t* lA[4];
    uint16_t* lB[4];
#pragma unroll
    for (int s = 0; s < 4; s++) {
        const int c   = tid + 256 * s;
        const int row = c >> 3;
        const int ql  = c & 7;
        const int qg  = ql ^ (row & 7);
        xg[s] = Xb + (size_t)(bm + row) * K_DIM + qg * 8;
        wg[s] = Wb + (size_t)(bn + row) * K_DIM + qg * 8;
        lA[s] = As + c * 8;
        lB[s] = Bs + c * 8;
    }

    const int m15 = lane & 15;     // fragment row/col index within 16
    const int kq  = lane >> 4;     // k-quad 0..3

    // Fragment LDS addresses (elements), with the same XOR swizzle:
    // chunk = row*8 + ((h*4 + kq) ^ (row & 7))
    int aoff[4][2], boff[4][2];
#pragma unroll
    for (int i = 0; i < 4; i++) {
        const int ra = wm + i * 16 + m15;
        const int rb = wn + i * 16 + m15;
#pragma unroll
        for (int h = 0; h < 2; h++) {
            const int kc = h * 4 + kq;
            aoff[i][h] = (ra * 8 + (kc ^ (ra & 7))) * 8;
            boff[i][h] = (rb * 8 + (kc ^ (rb & 7))) * 8;
        }
    }

    f32x4 acc[4][4];
    const f32x4 zero = {0.f, 0.f, 0.f, 0.f};
#pragma unroll
    for (int i = 0; i < 4; i++)
#pragma unroll
        for (int j = 0; j < 4; j++) acc[i][j] = zero;

    for (int k0 = 0; k0 < K_DIM; k0 += BK) {
#pragma unroll
        for (int s = 0; s < 4; s++) gload_lds16(xg[s] + k0, lA[s]);
#pragma unroll
        for (int s = 0; s < 4; s++) gload_lds16(wg[s] + k0, lB[s]);
        __syncthreads();

#pragma unroll
        for (int h = 0; h < 2; h++) {
            bf16x8 af[4], bfr[4];
#pragma unroll
            for (int i = 0; i < 4; i++) af[i]  = *(const bf16x8*)&As[aoff[i][h]];
#pragma unroll
            for (int j = 0; j < 4; j++) bfr[j] = *(const bf16x8*)&Bs[boff[j][h]];
#pragma unroll
            for (int i = 0; i < 4; i++)
#pragma unroll
                for (int j = 0; j < 4; j++)
                    acc[i][j] = __builtin_amdgcn_mfma_f32_16x16x32_bf16(af[i], bfr[j], acc[i][j], 0, 0, 0);
        }

        __syncthreads();
    }

    // Epilogue: C/D layout col = lane&15, row = (lane>>4)*4 + reg  [m89/m91]
#pragma unroll
    for (int j = 0; j < 4; j++) {
        const int col = bn + wn + j * 16 + m15;
        const float bv = bias[col];
#pragma unroll
        for (int i = 0; i < 4; i++) {
            const int row0 = bm + wm + i * 16 + kq * 4;
#pragma unroll
            for (int r = 0; r < 4; r++) {
                C[(size_t)(row0 + r) * N_DIM + col] = acc[i][j][r] + bv;
            }
        }
    }
}

extern "C" void kernel_launch(void* const* d_in, const int* in_sizes, int n_in,
                              void* d_out, int out_size, void* d_ws, size_t ws_size,
                              hipStream_t stream) {
    const float* x    = (const float*)d_in[0];
    const float* A    = (const float*)d_in[1];
    const float* B    = (const float*)d_in[2];
    const float* W    = (const float*)d_in[3];
    const float* bias = (const float*)d_in[4];
    float* out = (float*)d_out;

    uint16_t* Xb = (uint16_t*)d_ws;
    uint16_t* Wb = (uint16_t*)((char*)d_ws + (size_t)M_DIM * K_DIM * sizeof(uint16_t));

    prep_kernel<<<CVT_BLOCKS + N_DIM, 256, 0, stream>>>(x, Xb, W, A, B, Wb);

    dim3 grid(N_DIM / BN, M_DIM / BM);
    gemm_bt_bias<<<grid, 256, 0, stream>>>(Xb, Wb, bias, out);
}